// Round 1
// baseline (184.433 us; speedup 1.0000x reference)
//
#include <hip/hip_runtime.h>

// CoPE fused kernel, round R1.
// Changes vs R0 (173.7 us baseline):
//  1. prep_kernel + khi/klo workspace ELIMINATED: k is read as fp32 and split
//     to bf16 hi/lo inline in Phase B (same L2 bytes: 4B fp32 == 2B+2B hi/lo;
//     identical rounding -> bit-identical output). Removes one launch, 25 MB
//     of HBM traffic, and all d_ws usage (ws re-poison fill was 83 us/iter).
//  2. XCD-bijective block swizzle (nwg=2048 % 8 == 0): blocks of the same
//     batch share the K-quarter; swizzle puts 4 whole batches per XCD so the
//     per-XCD L2 fetches ~256 KB instead of ~2 MB (saves ~14 MB HBM FETCH).
//  3. Optimistic early broadcast: tab[63] region (cols 0..767, 75% of all
//     writes) is stored right after the table MFMA, hiding 48 KB/block of
//     writes under Phase B/D. Later quarters overwrite the same addresses
//     from the SAME lane (program-ordered) in the rare non-consensus case;
//     with this data min row-sum ~= 128 >> 63, so consensus always holds.

#define SLEN 1024
#define DDIM 64
#define NPOS 64
#define QROWS 16
#define QCOLS 256          // columns per quarter (processed right-to-left)
#define COPE_SCALE 0.125f
#define GSTR 260           // G row stride (words): 2-way max bank alias on scatter
#define TSTR 66            // table row stride: 2-way max

typedef __bf16 bf16x8 __attribute__((ext_vector_type(8)));
typedef float f32x4 __attribute__((ext_vector_type(4)));

__device__ __forceinline__ unsigned short f2bf_hi(float x) {
    unsigned u = __builtin_bit_cast(unsigned, x);
    unsigned r = u + 0x7FFFu + ((u >> 16) & 1u);
    return (unsigned short)(r >> 16);
}
__device__ __forceinline__ float bf2f(unsigned short h) {
    unsigned u = ((unsigned)h) << 16;
    return __builtin_bit_cast(float, u);
}
struct U8 { ushort4 a, b; };
__device__ __forceinline__ bf16x8 pack8(const unsigned short* s) {
    U8 u = {{s[0], s[1], s[2], s[3]}, {s[4], s[5], s[6], s[7]}};
    return __builtin_bit_cast(bf16x8, u);
}

// Load 16 fp32 from row ptr (d = +0..7 and +32..39) and split into bf16 hi/lo
// fragments. Rounding identical to the old prep_kernel -> bit-identical math.
__device__ __forceinline__ void load_split16(const float* __restrict__ row,
                                             bf16x8* hi, bf16x8* lo) {
    #pragma unroll
    for (int ks = 0; ks < 2; ++ks) {
        float4 v0 = *(const float4*)(row + ks * 32);
        float4 v1 = *(const float4*)(row + ks * 32 + 4);
        float xs[8] = {v0.x, v0.y, v0.z, v0.w, v1.x, v1.y, v1.z, v1.w};
        unsigned short hb[8], lb[8];
        #pragma unroll
        for (int j = 0; j < 8; ++j) {
            hb[j] = f2bf_hi(xs[j]);
            lb[j] = f2bf_hi(xs[j] - bf2f(hb[j]));
        }
        hi[ks] = pack8(hb);
        lo[ks] = pack8(lb);
    }
}

// ---------------- main MFMA kernel (single launch, no workspace) ----------------
__global__ __launch_bounds__(256, 6) void cope_mfma_kernel(
    const float* __restrict__ q,
    const float* __restrict__ k,
    const float* __restrict__ pos_emb,
    const int*   __restrict__ is_cope_k,
    float*       __restrict__ out)
{
    __shared__ __align__(16) float G[QROWS * GSTR];        // 16.6 KB (one quarter)
    __shared__ __align__(16) float tableL[QROWS * TSTR];   // 4.2 KB
    __shared__ float Racc[QROWS];                          // running suffix totals

    const int t = threadIdx.x;
    const int wave = t >> 6;
    const int lane = t & 63;
    const int quad = lane >> 4;
    const int nloc = lane & 15;

    // XCD-bijective swizzle: physical blockIdx round-robins XCDs (%8); map so
    // each XCD owns 4 contiguous batches -> K-quarter stays L2-resident.
    const int nwg = gridDim.x;
    const int phys = blockIdx.x;
    const int blk = ((nwg & 7) == 0) ? ((phys & 7) * (nwg >> 3) + (phys >> 3))
                                     : phys;
    const int batch = blk >> 6;           // SLEN/QROWS = 64 blocks per batch
    const int qbase = (blk & 63) * QROWS;

    if (t < QROWS) Racc[t] = 0.f;

    // ---- A fragments from q (split hi/lo): lane holds A[m=nloc][k=quad*8+j+ks*32] ----
    bf16x8 a_hi[2], a_lo[2];
    load_split16(q + (size_t)(batch * SLEN + qbase + nloc) * DDIM + quad * 8,
                 a_hi, a_lo);

    // ---- interp table via MFMA: table[m][n] = sum_d base[m][d] * pos_emb[d][n] ----
    {
        const int icope = *is_cope_k;   // wave-uniform
        bf16x8 t_hi[2], t_lo[2];
        if (icope) {
            t_hi[0] = a_hi[0]; t_hi[1] = a_hi[1];
            t_lo[0] = a_lo[0]; t_lo[1] = a_lo[1];
        } else {
            load_split16(k + (size_t)(batch * SLEN + qbase + nloc) * DDIM + quad * 8,
                         t_hi, t_lo);
        }
        bf16x8 p_hi[2];
        #pragma unroll
        for (int ks = 0; ks < 2; ++ks) {
            unsigned short hb[8];
            #pragma unroll
            for (int j = 0; j < 8; ++j) {
                float pv = pos_emb[(quad * 8 + j + ks * 32) * NPOS + wave * 16 + nloc];
                hb[j] = f2bf_hi(pv);
            }
            p_hi[ks] = pack8(hb);
        }
        f32x4 tacc = {0.f, 0.f, 0.f, 0.f};
        tacc = __builtin_amdgcn_mfma_f32_16x16x32_bf16(t_hi[0], p_hi[0], tacc, 0, 0, 0);
        tacc = __builtin_amdgcn_mfma_f32_16x16x32_bf16(t_lo[0], p_hi[0], tacc, 0, 0, 0);
        tacc = __builtin_amdgcn_mfma_f32_16x16x32_bf16(t_hi[1], p_hi[1], tacc, 0, 0, 0);
        tacc = __builtin_amdgcn_mfma_f32_16x16x32_bf16(t_lo[1], p_hi[1], tacc, 0, 0, 0);
        #pragma unroll
        for (int reg = 0; reg < 4; ++reg)
            tableL[(quad * 4 + reg) * TSTR + wave * 16 + nloc] = tacc[reg];
    }
    __syncthreads();   // table visible to all waves

    // ---- optimistic broadcast: cols 0..3*QCOLS-1 = tab[63] (clamped region).
    // Almost always final (consensus after quarter 3); otherwise later quarters
    // overwrite these exact addresses from the same lane (program-ordered).
    #pragma unroll
    for (int rep = 0; rep < 4; ++rep) {
        const int row = wave * 4 + rep;
        const float v63 = tableL[row * TSTR + (NPOS - 1)];
        f32x4 bv = {v63, v63, v63, v63};
        float* orow = out + (size_t)(batch * SLEN + qbase + row) * SLEN;
        #pragma unroll
        for (int c = 0; c < 3; ++c)
            __builtin_nontemporal_store(bv, (f32x4*)(orow + c * QCOLS + lane * 4));
    }

    // ---- quarters right-to-left; stop when every row's suffix total >= 63 ----
    for (int qi = 3; qi >= 0; --qi) {
        // Phase B: QK^T for this quarter (each wave: 4 of 16 tiles).
        // K is read as fp32 and hi/lo-split inline (no prep kernel / workspace).
        #pragma unroll
        for (int i = 0; i < 4; ++i) {
            const int tl = wave * 4 + i;
            const float* krow =
                k + (size_t)(batch * SLEN + qi * QCOLS + tl * 16 + nloc) * DDIM + quad * 8;
            bf16x8 bh[2], bl[2];
            load_split16(krow, bh, bl);
            f32x4 acc = {0.f, 0.f, 0.f, 0.f};
            acc = __builtin_amdgcn_mfma_f32_16x16x32_bf16(a_hi[0], bh[0], acc, 0, 0, 0);
            acc = __builtin_amdgcn_mfma_f32_16x16x32_bf16(a_lo[0], bh[0], acc, 0, 0, 0);
            acc = __builtin_amdgcn_mfma_f32_16x16x32_bf16(a_hi[0], bl[0], acc, 0, 0, 0);
            acc = __builtin_amdgcn_mfma_f32_16x16x32_bf16(a_hi[1], bh[1], acc, 0, 0, 0);
            acc = __builtin_amdgcn_mfma_f32_16x16x32_bf16(a_lo[1], bh[1], acc, 0, 0, 0);
            acc = __builtin_amdgcn_mfma_f32_16x16x32_bf16(a_hi[1], bl[1], acc, 0, 0, 0);
            // C/D layout: n = nloc (col), m = quad*4+reg (row)
            #pragma unroll
            for (int reg = 0; reg < 4; ++reg) {
                float x = acc[reg] * COPE_SCALE;
                float g = __builtin_amdgcn_rcpf(1.0f + __expf(-x));
                G[(quad * 4 + reg) * GSTR + tl * 16 + nloc] = g;
            }
        }
        __syncthreads();

        // Phase D: suffix scan + interp + store (each wave: 4 rows; lane: 4 cols)
        #pragma unroll
        for (int rep = 0; rep < 4; ++rep) {
            const int row = wave * 4 + rep;
            const float roff = Racc[row];
            float4 gv = *(const float4*)&G[row * GSTR + lane * 4];
            float ls3 = gv.w;
            float ls2 = gv.z + ls3;
            float ls1 = gv.y + ls2;
            float ls0 = gv.x + ls1;
            const float T = ls0;
            float v = T;
            #pragma unroll
            for (int ofs = 1; ofs < 64; ofs <<= 1) {
                float u = __shfl_down(v, ofs);
                if (lane + ofs < 64) v += u;
            }
            if (lane == 0) Racc[row] = roff + v;   // quarter total accumulates
            const float E = (v - T) + roff;

            const float tabv = tableL[row * TSTR + lane];   // tab[lane] in lane
            float dtabv = __shfl_down(tabv, 1) - tabv;      // tab[lane+1]-tab[lane]
            if (lane == 63) dtabv = 0.f;
            float ls[4] = {ls0, ls1, ls2, ls3};
            float res[4];
            #pragma unroll
            for (int i = 0; i < 4; ++i) {
                float p = ls[i] + E;
                p = fminf(p, (float)(NPOS - 1));
                float pf = floorf(p);
                int fi = (int)pf;
                float w = p - pf;
                float tf = __shfl(tabv, fi);
                float td = __shfl(dtabv, fi);
                res[i] = tf + w * td;
            }
            float* orow = out + (size_t)(batch * SLEN + qbase + row) * SLEN + qi * QCOLS + lane * 4;
            f32x4 o = {res[0], res[1], res[2], res[3]};
            __builtin_nontemporal_store(o, (f32x4*)orow);
        }
        __syncthreads();

        // done-check (uniform across block): all rows clamped below this quarter?
        float mn = Racc[0];
        #pragma unroll
        for (int r = 1; r < QROWS; ++r) mn = fminf(mn, Racc[r]);
        if (mn >= (float)(NPOS - 1)) break;   // remaining region already broadcast
    }
}

extern "C" void kernel_launch(void* const* d_in, const int* in_sizes, int n_in,
                              void* d_out, int out_size, void* d_ws, size_t ws_size,
                              hipStream_t stream) {
    (void)n_in; (void)out_size; (void)d_ws; (void)ws_size;
    const float* q         = (const float*)d_in[0];
    const float* k         = (const float*)d_in[1];
    const float* pos_emb   = (const float*)d_in[3];
    const int*   is_cope_k = (const int*)d_in[5];
    float* out = (float*)d_out;

    const int B = in_sizes[0] / (SLEN * DDIM);
    cope_mfma_kernel<<<B * (SLEN / QROWS), 256, 0, stream>>>(
        q, k, pos_emb, is_cope_k, out);
}

// Round 2
// 178.765 us; speedup vs baseline: 1.0317x; 1.0317x over previous
//
#include <hip/hip_runtime.h>

// CoPE fused kernel, round R2.
// Post-mortem R1: the 512 MiB ws poison fill is UNCONDITIONAL (ran with d_ws
// unused) -> ~105 us/iter of harness fills is a fixed floor. Inline k->bf16
// hi/lo conversion in Phase B re-converted each k row 64x/batch: +15 us VALU.
// R2: restore the prep kernel (conversion amortized once), but only convert
// the second half of each batch (quarters 0-1 are almost never processed:
// min row suffix-sum ~128 >> 63 after quarter 3). Hoist Phase B for qi=3
// before the table phase (its loads issue earliest, one sync fewer), keep
// XCD-bijective swizzle + optimistic early broadcast of the tab[63] region.

#define SLEN 1024
#define DDIM 64
#define NPOS 64
#define QROWS 16
#define QCOLS 256          // columns per quarter (processed right-to-left)
#define COPE_SCALE 0.125f
#define GSTR 260           // G row stride (words): 2-way max bank alias on scatter
#define TSTR 66            // table row stride: 2-way max

typedef __bf16 bf16x8 __attribute__((ext_vector_type(8)));
typedef float f32x4 __attribute__((ext_vector_type(4)));

__device__ __forceinline__ unsigned short f2bf_hi(float x) {
    unsigned u = __builtin_bit_cast(unsigned, x);
    unsigned r = u + 0x7FFFu + ((u >> 16) & 1u);
    return (unsigned short)(r >> 16);
}
__device__ __forceinline__ float bf2f(unsigned short h) {
    unsigned u = ((unsigned)h) << 16;
    return __builtin_bit_cast(float, u);
}
struct U8 { ushort4 a, b; };
__device__ __forceinline__ bf16x8 pack8(const unsigned short* s) {
    U8 u = {{s[0], s[1], s[2], s[3]}, {s[4], s[5], s[6], s[7]}};
    return __builtin_bit_cast(bf16x8, u);
}

// Load 16 fp32 (d = +0..7 and +32..39) and split into bf16 hi/lo fragments.
// Rounding identical to prep_kernel -> bit-identical results on either path.
__device__ __forceinline__ void load_split16(const float* __restrict__ row,
                                             bf16x8* hi, bf16x8* lo) {
    #pragma unroll
    for (int ks = 0; ks < 2; ++ks) {
        float4 v0 = *(const float4*)(row + ks * 32);
        float4 v1 = *(const float4*)(row + ks * 32 + 4);
        float xs[8] = {v0.x, v0.y, v0.z, v0.w, v1.x, v1.y, v1.z, v1.w};
        unsigned short hb[8], lb[8];
        #pragma unroll
        for (int j = 0; j < 8; ++j) {
            hb[j] = f2bf_hi(xs[j]);
            lb[j] = f2bf_hi(xs[j] - bf2f(hb[j]));
        }
        hi[ks] = pack8(hb);
        lo[ks] = pack8(lb);
    }
}

// ---------------- prep: split SECOND HALF of each batch of k into bf16 hi+lo ----------------
// Quarters 2-3 (cols 512..1023) are the only ones the main kernel normally
// touches; qi<=1 falls back to inline conversion (bit-identical, ~never runs).
__global__ __launch_bounds__(256) void prep_kernel(
    const float* __restrict__ k,
    unsigned short* __restrict__ khi,
    unsigned short* __restrict__ klo,
    int n4h)                                   // float4 count over all half-batches
{
    int j = blockIdx.x * 256 + threadIdx.x;
    if (j >= n4h) return;
    const int HB4 = (SLEN / 2) * DDIM / 4;     // 8192 float4 per half-batch
    int batch = j / HB4;
    int rem   = j - batch * HB4;
    int i = batch * (SLEN * DDIM / 4) + HB4 + rem;   // absolute float4 index
    float4 v = ((const float4*)k)[i];
    ushort4 h, l;
    h.x = f2bf_hi(v.x); l.x = f2bf_hi(v.x - bf2f(h.x));
    h.y = f2bf_hi(v.y); l.y = f2bf_hi(v.y - bf2f(h.y));
    h.z = f2bf_hi(v.z); l.z = f2bf_hi(v.z - bf2f(h.z));
    h.w = f2bf_hi(v.w); l.w = f2bf_hi(v.w - bf2f(h.w));
    ((ushort4*)khi)[i] = h;
    ((ushort4*)klo)[i] = l;
}

// ---------------- main MFMA kernel ----------------
__global__ __launch_bounds__(256, 6) void cope_mfma_kernel(
    const float* __restrict__ q,
    const float* __restrict__ k,
    const float* __restrict__ pos_emb,
    const int*   __restrict__ is_cope_k,
    const unsigned short* __restrict__ khi,
    const unsigned short* __restrict__ klo,
    int ws_ok,
    float*       __restrict__ out)
{
    __shared__ __align__(16) float G[QROWS * GSTR];        // 16.6 KB (one quarter)
    __shared__ __align__(16) float tableL[QROWS * TSTR];   // 4.2 KB
    __shared__ float Racc[QROWS];                          // running suffix totals

    const int t = threadIdx.x;
    const int wave = t >> 6;
    const int lane = t & 63;
    const int quad = lane >> 4;
    const int nloc = lane & 15;

    // XCD-bijective swizzle (nwg = 2048, %8 == 0): each XCD owns 4 contiguous
    // batches so the shared K-quarter stays resident in its private L2.
    const int nwg = gridDim.x;
    const int phys = blockIdx.x;
    const int blk = ((nwg & 7) == 0) ? ((phys & 7) * (nwg >> 3) + (phys >> 3))
                                     : phys;
    const int batch = blk >> 6;           // SLEN/QROWS = 64 blocks per batch
    const int qbase = (blk & 63) * QROWS;

    if (t < QROWS) Racc[t] = 0.f;

    // ---- A fragments from q (split hi/lo): lane holds A[m=nloc][k=quad*8+j+ks*32] ----
    bf16x8 a_hi[2], a_lo[2];
    load_split16(q + (size_t)(batch * SLEN + qbase + nloc) * DDIM + quad * 8,
                 a_hi, a_lo);

    // ---- Phase B: QK^T gates for one quarter into G (each wave: 4 of 16 tiles) ----
    auto phaseB = [&](int qi, bool use_ws) {
        #pragma unroll
        for (int i = 0; i < 4; ++i) {
            const int tl = wave * 4 + i;
            const size_t boff =
                (size_t)(batch * SLEN + qi * QCOLS + tl * 16 + nloc) * DDIM + quad * 8;
            bf16x8 bh[2], bl[2];
            if (use_ws) {
                bh[0] = __builtin_bit_cast(bf16x8, *(const uint4*)(khi + boff));
                bh[1] = __builtin_bit_cast(bf16x8, *(const uint4*)(khi + boff + 32));
                bl[0] = __builtin_bit_cast(bf16x8, *(const uint4*)(klo + boff));
                bl[1] = __builtin_bit_cast(bf16x8, *(const uint4*)(klo + boff + 32));
            } else {
                load_split16(k + boff, bh, bl);   // cold path (qi<=1 or no ws)
            }
            f32x4 acc = {0.f, 0.f, 0.f, 0.f};
            acc = __builtin_amdgcn_mfma_f32_16x16x32_bf16(a_hi[0], bh[0], acc, 0, 0, 0);
            acc = __builtin_amdgcn_mfma_f32_16x16x32_bf16(a_lo[0], bh[0], acc, 0, 0, 0);
            acc = __builtin_amdgcn_mfma_f32_16x16x32_bf16(a_hi[0], bl[0], acc, 0, 0, 0);
            acc = __builtin_amdgcn_mfma_f32_16x16x32_bf16(a_hi[1], bh[1], acc, 0, 0, 0);
            acc = __builtin_amdgcn_mfma_f32_16x16x32_bf16(a_lo[1], bh[1], acc, 0, 0, 0);
            acc = __builtin_amdgcn_mfma_f32_16x16x32_bf16(a_hi[1], bl[1], acc, 0, 0, 0);
            // C/D layout: n = nloc (col), m = quad*4+reg (row)
            #pragma unroll
            for (int reg = 0; reg < 4; ++reg) {
                float x = acc[reg] * COPE_SCALE;
                float g = __builtin_amdgcn_rcpf(1.0f + __expf(-x));
                G[(quad * 4 + reg) * GSTR + tl * 16 + nloc] = g;
            }
        }
    };

    // ---- Phase D: suffix scan + interp + store (each wave: 4 rows; lane: 4 cols) ----
    auto phaseD = [&](int qi) {
        #pragma unroll
        for (int rep = 0; rep < 4; ++rep) {
            const int row = wave * 4 + rep;
            const float roff = Racc[row];
            float4 gv = *(const float4*)&G[row * GSTR + lane * 4];
            float ls3 = gv.w;
            float ls2 = gv.z + ls3;
            float ls1 = gv.y + ls2;
            float ls0 = gv.x + ls1;
            const float T = ls0;
            float v = T;
            #pragma unroll
            for (int ofs = 1; ofs < 64; ofs <<= 1) {
                float u = __shfl_down(v, ofs);
                if (lane + ofs < 64) v += u;
            }
            if (lane == 0) Racc[row] = roff + v;   // quarter total accumulates
            const float E = (v - T) + roff;

            const float tabv = tableL[row * TSTR + lane];   // tab[lane] in lane
            float dtabv = __shfl_down(tabv, 1) - tabv;      // tab[lane+1]-tab[lane]
            if (lane == 63) dtabv = 0.f;
            float ls[4] = {ls0, ls1, ls2, ls3};
            float res[4];
            #pragma unroll
            for (int i = 0; i < 4; ++i) {
                float p = ls[i] + E;
                p = fminf(p, (float)(NPOS - 1));
                float pf = floorf(p);
                int fi = (int)pf;
                float w = p - pf;
                float tf = __shfl(tabv, fi);
                float td = __shfl(dtabv, fi);
                res[i] = tf + w * td;
            }
            float* orow = out + (size_t)(batch * SLEN + qbase + row) * SLEN + qi * QCOLS + lane * 4;
            f32x4 o = {res[0], res[1], res[2], res[3]};
            __builtin_nontemporal_store(o, (f32x4*)orow);
        }
    };

    // ---- Phase B for qi=3 FIRST: its 64 B/lane loads issue earliest; no table dep ----
    phaseB(3, ws_ok != 0);

    // ---- interp table via MFMA: table[m][n] = sum_d base[m][d] * pos_emb[d][n] ----
    {
        const int icope = *is_cope_k;   // wave-uniform
        bf16x8 t_hi[2], t_lo[2];
        if (icope) {
            t_hi[0] = a_hi[0]; t_hi[1] = a_hi[1];
            t_lo[0] = a_lo[0]; t_lo[1] = a_lo[1];
        } else {
            load_split16(k + (size_t)(batch * SLEN + qbase + nloc) * DDIM + quad * 8,
                         t_hi, t_lo);
        }
        bf16x8 p_hi[2];
        #pragma unroll
        for (int ks = 0; ks < 2; ++ks) {
            unsigned short hb[8];
            #pragma unroll
            for (int j = 0; j < 8; ++j) {
                float pv = pos_emb[(quad * 8 + j + ks * 32) * NPOS + wave * 16 + nloc];
                hb[j] = f2bf_hi(pv);
            }
            p_hi[ks] = pack8(hb);
        }
        f32x4 tacc = {0.f, 0.f, 0.f, 0.f};
        tacc = __builtin_amdgcn_mfma_f32_16x16x32_bf16(t_hi[0], p_hi[0], tacc, 0, 0, 0);
        tacc = __builtin_amdgcn_mfma_f32_16x16x32_bf16(t_lo[0], p_hi[0], tacc, 0, 0, 0);
        tacc = __builtin_amdgcn_mfma_f32_16x16x32_bf16(t_hi[1], p_hi[1], tacc, 0, 0, 0);
        tacc = __builtin_amdgcn_mfma_f32_16x16x32_bf16(t_lo[1], p_hi[1], tacc, 0, 0, 0);
        #pragma unroll
        for (int reg = 0; reg < 4; ++reg)
            tableL[(quad * 4 + reg) * TSTR + wave * 16 + nloc] = tacc[reg];
    }
    __syncthreads();   // covers G (qi=3) + tableL stores

    // ---- optimistic broadcast: cols 0..3*QCOLS-1 = tab[63] (clamped region).
    // Almost always final; otherwise later quarters overwrite the same
    // addresses from the SAME lane (program-ordered within thread -> safe).
    #pragma unroll
    for (int rep = 0; rep < 4; ++rep) {
        const int row = wave * 4 + rep;
        const float v63 = tableL[row * TSTR + (NPOS - 1)];
        f32x4 bv = {v63, v63, v63, v63};
        float* orow = out + (size_t)(batch * SLEN + qbase + row) * SLEN;
        #pragma unroll
        for (int c = 0; c < 3; ++c)
            __builtin_nontemporal_store(bv, (f32x4*)(orow + c * QCOLS + lane * 4));
    }

    phaseD(3);
    __syncthreads();

    // done-check (uniform across block): all rows clamped left of quarter 3?
    {
        float mn = Racc[0];
        #pragma unroll
        for (int r = 1; r < QROWS; ++r) mn = fminf(mn, Racc[r]);
        if (mn >= (float)(NPOS - 1)) return;   // rest already broadcast
    }

    // ---- rare path: continue quarters right-to-left ----
    for (int qi = 2; qi >= 0; --qi) {
        phaseB(qi, ws_ok != 0 && qi >= 2);   // khi/klo only covers cols >= 512
        __syncthreads();
        phaseD(qi);
        __syncthreads();
        float mn = Racc[0];
        #pragma unroll
        for (int r = 1; r < QROWS; ++r) mn = fminf(mn, Racc[r]);
        if (mn >= (float)(NPOS - 1)) break;
    }
}

extern "C" void kernel_launch(void* const* d_in, const int* in_sizes, int n_in,
                              void* d_out, int out_size, void* d_ws, size_t ws_size,
                              hipStream_t stream) {
    (void)n_in; (void)out_size;
    const float* q         = (const float*)d_in[0];
    const float* k         = (const float*)d_in[1];
    const float* pos_emb   = (const float*)d_in[3];
    const int*   is_cope_k = (const int*)d_in[5];
    float* out = (float*)d_out;

    const int nk = in_sizes[1];                 // B*S*D
    const int B = in_sizes[0] / (SLEN * DDIM);
    const size_t ws_need = (size_t)nk * 2 * sizeof(unsigned short);  // khi + klo

    unsigned short* khi = (unsigned short*)d_ws;
    unsigned short* klo = khi + nk;
    const int ws_ok = (ws_size >= ws_need) ? 1 : 0;

    if (ws_ok) {
        int n4h = nk / 8;                       // float4s in all half-batches
        prep_kernel<<<(n4h + 255) / 256, 256, 0, stream>>>(k, khi, klo, n4h);
    }
    cope_mfma_kernel<<<B * (SLEN / QROWS), 256, 0, stream>>>(
        q, k, pos_emb, is_cope_k, khi, klo, ws_ok, out);
}